// Round 8
// baseline (440.949 us; speedup 1.0000x reference)
//
#include <hip/hip_runtime.h>
#include <hip/hip_bf16.h>
#include <cstddef>
#include <cstdint>

namespace {
constexpr int Bn = 4, SEQ = 2048, CDIM = 1024, NH = 16, DH = 64;
constexpr int Mrows = Bn * SEQ;  // 8192
}

using bf16x8 = __attribute__((ext_vector_type(8))) __bf16;
using f32x4  = __attribute__((ext_vector_type(4))) float;
using f32x16 = __attribute__((ext_vector_type(16))) float;

#define MFMA16(a, b, c) __builtin_amdgcn_mfma_f32_16x16x32_bf16(a, b, c, 0, 0, 0)
#define MFMA32(a, b, c) __builtin_amdgcn_mfma_f32_32x32x16_bf16(a, b, c, 0, 0, 0)

__device__ __forceinline__ void gload_lds16(const __bf16* g, __bf16* l) {
  __builtin_amdgcn_global_load_lds(
      (const __attribute__((address_space(1))) void*)g,
      (__attribute__((address_space(3))) void*)l, 16, 0, 0);
}

__device__ __forceinline__ unsigned pk2(float a, float b) {
  union { __bf16 h[2]; unsigned u; } x;
  x.h[0] = (__bf16)a; x.h[1] = (__bf16)b;
  return x.u;
}

// ---------------------------------------------------------------------------
// Cast x and the 4 weight matrices to bf16.  wall rows: [Wq;Wk;Wv;Wo].
// ---------------------------------------------------------------------------
__global__ __launch_bounds__(256) void cast_inputs(
    const float* __restrict__ x, const float* __restrict__ wq,
    const float* __restrict__ wk, const float* __restrict__ wv,
    const float* __restrict__ wo, __bf16* __restrict__ xb,
    __bf16* __restrict__ wall) {
  constexpr int X4 = Mrows * CDIM / 4;  // 2M float4
  constexpr int W4 = CDIM * CDIM / 4;   // 256K float4 (== 1<<18)
  constexpr int total = X4 + 4 * W4;
  for (int i = blockIdx.x * 256 + threadIdx.x; i < total; i += gridDim.x * 256) {
    const float4* src;
    __bf16* dst;
    int o;
    if (i < X4) {
      src = (const float4*)x; dst = xb; o = i;
    } else {
      int j = i - X4;
      int w = j >> 18;
      o = j & (W4 - 1);
      src = (const float4*)(w == 0 ? wq : w == 1 ? wk : w == 2 ? wv : wo);
      dst = wall + (size_t)w * (CDIM * CDIM);
    }
    float4 v = src[o];
    union { __bf16 h[4]; ushort4 u4; } pk;
    pk.h[0] = (__bf16)v.x; pk.h[1] = (__bf16)v.y;
    pk.h[2] = (__bf16)v.z; pk.h[3] = (__bf16)v.w;
    *(ushort4*)(dst + (size_t)o * 4) = pk.u4;
  }
}

// ---------------------------------------------------------------------------
// bf16 MFMA GEMM (m97 structure, verified rounds 3-7).
// MODE 1: N=3072 fused QKV.  Q (scaled by 0.125*log2e, for exp2-domain
//   softmax) and K -> [B,H,N,Dh];  V -> TRANSPOSED [B,H,Dh,SEQ] so attention
//   can load V^T A-fragments straight from global (no LDS transpose).
// MODE 0: N=1024 -> fp32 out + bias, row-major [M,1024]
// ---------------------------------------------------------------------------
template <int MODE>
__global__ __launch_bounds__(256) void gemm_mfma(
    const __bf16* __restrict__ A, const __bf16* __restrict__ Bw,
    const float* __restrict__ b0, const float* __restrict__ b1,
    const float* __restrict__ b2, __bf16* __restrict__ Qb,
    __bf16* __restrict__ Kb, __bf16* __restrict__ Vb,
    float* __restrict__ Yf) {
  __shared__ __align__(16) __bf16 As[128 * 32];
  __shared__ __align__(16) __bf16 Bs[128 * 32];
  const int tid = threadIdx.x;
  const int lane = tid & 63, w = tid >> 6;
  const int wr = w >> 1, wc = w & 1;
  const int l4 = lane >> 4, l15 = lane & 15;
  const int m0 = blockIdx.y * 128, n0 = blockIdx.x * 128;

  f32x4 acc[4][4] = {};
  const int srow = lane >> 2;
  const int scol = (lane & 3) * 8;

  for (int k0 = 0; k0 < CDIM; k0 += 32) {
    __syncthreads();
#pragma unroll
    for (int u = 0; u < 2; ++u) {
      const int c = w * 2 + u;
      gload_lds16(A + (size_t)(m0 + c * 16 + srow) * CDIM + k0 + scol,
                  &As[c * 512]);
      gload_lds16(Bw + (size_t)(n0 + c * 16 + srow) * CDIM + k0 + scol,
                  &Bs[c * 512]);
    }
    __syncthreads();
    bf16x8 af[4], bfr[4];
#pragma unroll
    for (int i = 0; i < 4; ++i)
      af[i] = *(const bf16x8*)&As[(wr * 64 + i * 16 + l15) * 32 + l4 * 8];
#pragma unroll
    for (int j = 0; j < 4; ++j)
      bfr[j] = *(const bf16x8*)&Bs[(wc * 64 + j * 16 + l15) * 32 + l4 * 8];
#pragma unroll
    for (int i = 0; i < 4; ++i)
#pragma unroll
      for (int j = 0; j < 4; ++j)
        acc[i][j] = MFMA16(af[i], bfr[j], acc[i][j]);
  }

  const int row0 = m0 + wr * 64;
  if (MODE == 0) {
#pragma unroll
    for (int j = 0; j < 4; ++j) {
      const int n = (n0 + wc * 64 + j * 16) + l15;
      const float bias = b0[n];
#pragma unroll
      for (int i = 0; i < 4; ++i) {
        const int mrow = row0 + i * 16 + l4 * 4;
#pragma unroll
        for (int r = 0; r < 4; ++r)
          Yf[(size_t)(mrow + r) * CDIM + n] = acc[i][j][r] + bias;
      }
    }
  } else {
    const int which = n0 >> 10;  // 0=q 1=k 2=v (block-uniform)
    const float* bias = which == 0 ? b0 : which == 1 ? b1 : b2;
    const int n0c = n0 & 1023;
    if (which == 2) {
      // V^T store: [B][H][Dh][SEQ]
#pragma unroll
      for (int j = 0; j < 4; ++j) {
        const int c = n0c + wc * 64 + j * 16 + l15;
        const int h = c >> 6, dh = c & 63;
        const float bias_v = bias[c];
#pragma unroll
        for (int i = 0; i < 4; ++i) {
          const int mrow = row0 + i * 16 + l4 * 4;
          const int b_ = mrow >> 11, ns = mrow & (SEQ - 1);
          __bf16* p = Vb + ((size_t)(b_ * NH + h) * DH + dh) * SEQ + ns;
          *(unsigned*)p = pk2(acc[i][j][0] + bias_v, acc[i][j][1] + bias_v);
          *(unsigned*)(p + 2) = pk2(acc[i][j][2] + bias_v, acc[i][j][3] + bias_v);
        }
      }
    } else {
      __bf16* Out = which == 0 ? Qb : Kb;
      // Q scale: Dh^-0.5 * log2(e)  (softmax runs in exp2 domain)
      const float scl = which == 0 ? 0.18033688f : 1.0f;
#pragma unroll
      for (int j = 0; j < 4; ++j) {
        const int c = n0c + wc * 64 + j * 16 + l15;
        const int h = c >> 6, dh = c & 63;
        const float bias_v = bias[c];
#pragma unroll
        for (int i = 0; i < 4; ++i) {
          const int mrow = row0 + i * 16 + l4 * 4;
#pragma unroll
          for (int r = 0; r < 4; ++r) {
            const int m = mrow + r;
            const int b_ = m >> 11, ns = m & (SEQ - 1);
            Out[((size_t)(b_ * NH + h) * SEQ + ns) * DH + dh] =
                (__bf16)((acc[i][j][r] + bias_v) * scl);
          }
        }
      }
    }
  }
}

// ---------------------------------------------------------------------------
// Flash attention v5: BARRIER-FREE, LDS-FREE.  1 wave per block, 32 q-rows.
// QK^T: S^T = mfma(K-frag, Q-frag) with K fragments loaded直接 from global
// (L2-hot).  PV: O^T = mfma(V^T-frag, P^T-frag) with V^T fragments loaded
// straight from the transposed V produced by the QKV GEMM.  Softmax fully
// in-register (exp2 domain), P exchanged via 8 shfl_xor(32).  No
// __syncthreads anywhere -> no vmcnt(0) barrier drains, no wave lockstep;
// latency hidden by independent waves + compiler pipelining.
// ---------------------------------------------------------------------------
__global__ __launch_bounds__(64) void attn_mfma(
    const __bf16* __restrict__ Qg, const __bf16* __restrict__ Kg,
    const __bf16* __restrict__ VTg, __bf16* __restrict__ AO) {
  const int lane = threadIdx.x & 63;
  const int l31 = lane & 31, hi = lane >> 5;
  const int bh = blockIdx.x, qt = blockIdx.y;
  const int b_ = bh >> 4, h_ = bh & 15;

  const __bf16* Qp = Qg + ((size_t)bh * SEQ + qt * 32) * DH;
  const __bf16* Kb = Kg + (size_t)bh * SEQ * DH;
  const __bf16* VT = VTg + (size_t)bh * DH * SEQ;  // [d][seq]

  // Q B-frags: lane holds Q[q=l31][d = t*16 + hi*8 + e]  (pre-scaled)
  bf16x8 q[4];
#pragma unroll
  for (int t = 0; t < 4; ++t)
    q[t] = *(const bf16x8*)(Qp + (size_t)l31 * DH + t * 16 + hi * 8);

  f32x16 o0 = {}, o1 = {};  // O^T: lane q=l31, d = X*32 + (j&3)+8*(j>>2)+4*hi
  float m_i = -1e30f, l_i = 0.f;

#pragma unroll 2
  for (int kt = 0; kt < 32; ++kt) {
    const __bf16* Kt = Kb + (size_t)kt * 64 * DH;
    const __bf16* Vt = VT + kt * 64;
    // Swapped QK^T: s[X] holds S[key = X*32 + (reg&3)+8*(reg>>2)+4*hi][q=l31]
    f32x16 s0 = {}, s1 = {};
#pragma unroll
    for (int t = 0; t < 4; ++t) {
      bf16x8 ka = *(const bf16x8*)(Kt + (size_t)l31 * DH + t * 16 + hi * 8);
      s0 = MFMA32(ka, q[t], s0);
    }
#pragma unroll
    for (int t = 0; t < 4; ++t) {
      bf16x8 kc = *(const bf16x8*)(Kt + (size_t)(32 + l31) * DH + t * 16 + hi * 8);
      s1 = MFMA32(kc, q[t], s1);
    }
    // ---- softmax (exp2 domain; Q pre-scaled by 0.125*log2e) ----
    float mt[16];
#pragma unroll
    for (int j = 0; j < 16; ++j) mt[j] = fmaxf(s0[j], s1[j]);
#pragma unroll
    for (int st = 8; st > 0; st >>= 1)
#pragma unroll
      for (int j = 0; j < 8; ++j)
        if (j < st) mt[j] = fmaxf(mt[j], mt[j + st]);
    float mx = fmaxf(mt[0], __shfl_xor(mt[0], 32));
    if (!__all(mx <= m_i + 8.0f)) {  // defer-max (P bounded by 2^8)
      const float mnew = fmaxf(m_i, mx);
      const float alpha = __builtin_amdgcn_exp2f(m_i - mnew);
      m_i = mnew;
      l_i *= alpha;
      o0 *= alpha;
      o1 *= alpha;
    }
    // exp2 + pack:  W[X][m][j2] = bf16x2 of keys (X*32 + 8m+4hi+2j2, +1)
    unsigned W0[4][2], W1[4][2];
    float psa[4] = {0.f, 0.f, 0.f, 0.f};
#pragma unroll
    for (int m = 0; m < 4; ++m)
#pragma unroll
      for (int j2 = 0; j2 < 2; ++j2) {
        float a0 = __builtin_amdgcn_exp2f(s0[4 * m + 2 * j2] - m_i);
        float a1 = __builtin_amdgcn_exp2f(s0[4 * m + 2 * j2 + 1] - m_i);
        float b0 = __builtin_amdgcn_exp2f(s1[4 * m + 2 * j2] - m_i);
        float b1 = __builtin_amdgcn_exp2f(s1[4 * m + 2 * j2 + 1] - m_i);
        psa[m] += (a0 + a1) + (b0 + b1);
        W0[m][j2] = pk2(a0, a1);
        W1[m][j2] = pk2(b0, b1);
      }
    float ps = (psa[0] + psa[1]) + (psa[2] + psa[3]);
    ps += __shfl_xor(ps, 32);
    l_i += ps;
    // ---- exchange -> P^T B-frags Bp[ks]: key=ks*16+hi*8+e, col q=l31 ----
    bf16x8 Bp[4];
#pragma unroll
    for (int X = 0; X < 2; ++X)
#pragma unroll
      for (int k2 = 0; k2 < 2; ++k2) {
        union { unsigned u[4]; bf16x8 v; } bb;
#pragma unroll
        for (int j2 = 0; j2 < 2; ++j2) {
          const unsigned a = X ? W1[2 * k2][j2] : W0[2 * k2][j2];
          const unsigned b = X ? W1[2 * k2 + 1][j2] : W0[2 * k2 + 1][j2];
          const unsigned snd = hi ? a : b;
          const unsigned rcv = __shfl_xor(snd, 32);
          bb.u[j2] = hi ? rcv : a;
          bb.u[2 + j2] = hi ? b : rcv;
        }
        Bp[X * 2 + k2] = bb.v;
      }
    // ---- PV: O^T += V^T-frag x P^T-frag  (V^T直接 from global) ----
#pragma unroll
    for (int ks = 0; ks < 4; ++ks) {
      bf16x8 va0 = *(const bf16x8*)(Vt + (size_t)l31 * SEQ + ks * 16 + hi * 8);
      bf16x8 va1 =
          *(const bf16x8*)(Vt + (size_t)(32 + l31) * SEQ + ks * 16 + hi * 8);
      o0 = MFMA32(va0, Bp[ks], o0);
      o1 = MFMA32(va1, Bp[ks], o1);
    }
  }

  // epilogue: lane q=l31; d = X*32 + 8*(u>>1) + 4*hi + 2*(u&1) for reg pair
  // (2u, 2u+1); pack pairs, u32 stores to AO[b, q, h*64 + d].
  const float inv = 1.f / l_i;
  const int qglob = qt * 32 + l31;
  __bf16* aorow = AO + ((size_t)(b_ * SEQ) + qglob) * CDIM + h_ * DH;
#pragma unroll
  for (int u = 0; u < 8; ++u) {
    const int dbase = 8 * (u >> 1) + 4 * hi + 2 * (u & 1);
    *(unsigned*)(aorow + dbase) = pk2(o0[2 * u] * inv, o0[2 * u + 1] * inv);
    *(unsigned*)(aorow + 32 + dbase) = pk2(o1[2 * u] * inv, o1[2 * u + 1] * inv);
  }
}

// ---------------------------------------------------------------------------
extern "C" void kernel_launch(void* const* d_in, const int* in_sizes, int n_in,
                              void* d_out, int out_size, void* d_ws,
                              size_t ws_size, hipStream_t stream) {
  const float* x  = (const float*)d_in[0];
  const float* Wq = (const float*)d_in[1];
  const float* bq = (const float*)d_in[2];
  const float* Wk = (const float*)d_in[3];
  const float* bk = (const float*)d_in[4];
  const float* Wv = (const float*)d_in[5];
  const float* bv = (const float*)d_in[6];
  const float* Wo = (const float*)d_in[7];
  const float* bo = (const float*)d_in[8];
  float* out = (float*)d_out;

  __bf16* xb   = (__bf16*)d_ws;
  __bf16* wall = xb + (size_t)Mrows * CDIM;
  __bf16* Qb   = wall + (size_t)4 * CDIM * CDIM;
  __bf16* Kb   = Qb + (size_t)Mrows * CDIM;
  __bf16* Vt   = Kb + (size_t)Mrows * CDIM;   // V^T [B][H][Dh][SEQ]
  __bf16* AO   = Vt + (size_t)Mrows * CDIM;

  cast_inputs<<<2048, 256, 0, stream>>>(x, Wq, Wk, Wv, Wo, xb, wall);
  gemm_mfma<1><<<dim3(24, 64), 256, 0, stream>>>(xb, wall, bq, bk, bv, Qb, Kb,
                                                 Vt, nullptr);
  attn_mfma<<<dim3(Bn * NH, SEQ / 32), 64, 0, stream>>>(Qb, Kb, Vt, AO);
  gemm_mfma<0><<<dim3(8, 64), 256, 0, stream>>>(
      AO, wall + (size_t)3 * CDIM * CDIM, bo, nullptr, nullptr, nullptr,
      nullptr, nullptr, out);
}

// Round 9
// 322.712 us; speedup vs baseline: 1.3664x; 1.3664x over previous
//
#include <hip/hip_runtime.h>
#include <hip/hip_bf16.h>
#include <cstddef>
#include <cstdint>

namespace {
constexpr int Bn = 4, SEQ = 2048, CDIM = 1024, NH = 16, DH = 64;
constexpr int Mrows = Bn * SEQ;  // 8192
}

using bf16x8 = __attribute__((ext_vector_type(8))) __bf16;
using f32x4  = __attribute__((ext_vector_type(4))) float;
using f32x16 = __attribute__((ext_vector_type(16))) float;

#define MFMA16(a, b, c) __builtin_amdgcn_mfma_f32_16x16x32_bf16(a, b, c, 0, 0, 0)
#define MFMA32(a, b, c) __builtin_amdgcn_mfma_f32_32x32x16_bf16(a, b, c, 0, 0, 0)

__device__ __forceinline__ void gload_lds16(const __bf16* g, __bf16* l) {
  __builtin_amdgcn_global_load_lds(
      (const __attribute__((address_space(1))) void*)g,
      (__attribute__((address_space(3))) void*)l, 16, 0, 0);
}

__device__ __forceinline__ unsigned pk2(float a, float b) {
  union { __bf16 h[2]; unsigned u; } x;
  x.h[0] = (__bf16)a; x.h[1] = (__bf16)b;
  return x.u;
}

// Raw barrier: waits own DS ops (so our ds_writes are visible) but does NOT
// drain vmcnt -- prefetch global loads stay in flight across it (T4).
__device__ __forceinline__ void block_sync_lds() {
  asm volatile("s_waitcnt lgkmcnt(0)" ::: "memory");
  __builtin_amdgcn_s_barrier();
}

// ---------------------------------------------------------------------------
// Cast x and the 4 weight matrices to bf16.  wall rows: [Wq;Wk;Wv;Wo].
// ---------------------------------------------------------------------------
__global__ __launch_bounds__(256) void cast_inputs(
    const float* __restrict__ x, const float* __restrict__ wq,
    const float* __restrict__ wk, const float* __restrict__ wv,
    const float* __restrict__ wo, __bf16* __restrict__ xb,
    __bf16* __restrict__ wall) {
  constexpr int X4 = Mrows * CDIM / 4;  // 2M float4
  constexpr int W4 = CDIM * CDIM / 4;   // 256K float4 (== 1<<18)
  constexpr int total = X4 + 4 * W4;
  for (int i = blockIdx.x * 256 + threadIdx.x; i < total; i += gridDim.x * 256) {
    const float4* src;
    __bf16* dst;
    int o;
    if (i < X4) {
      src = (const float4*)x; dst = xb; o = i;
    } else {
      int j = i - X4;
      int w = j >> 18;
      o = j & (W4 - 1);
      src = (const float4*)(w == 0 ? wq : w == 1 ? wk : w == 2 ? wv : wo);
      dst = wall + (size_t)w * (CDIM * CDIM);
    }
    float4 v = src[o];
    union { __bf16 h[4]; ushort4 u4; } pk;
    pk.h[0] = (__bf16)v.x; pk.h[1] = (__bf16)v.y;
    pk.h[2] = (__bf16)v.z; pk.h[3] = (__bf16)v.w;
    *(ushort4*)(dst + (size_t)o * 4) = pk.u4;
  }
}

// ---------------------------------------------------------------------------
// bf16 MFMA GEMM (m97 structure, verified rounds 3-8).
// MODE 1: N=3072 fused QKV.  Q scaled by 0.125*log2e (exp2-domain softmax)
//   and K -> [B,H,N,Dh];  V -> TRANSPOSED [B,H,Dh,SEQ].
// MODE 0: N=1024 -> fp32 out + bias, row-major [M,1024]
// ---------------------------------------------------------------------------
template <int MODE>
__global__ __launch_bounds__(256) void gemm_mfma(
    const __bf16* __restrict__ A, const __bf16* __restrict__ Bw,
    const float* __restrict__ b0, const float* __restrict__ b1,
    const float* __restrict__ b2, __bf16* __restrict__ Qb,
    __bf16* __restrict__ Kb, __bf16* __restrict__ Vb,
    float* __restrict__ Yf) {
  __shared__ __align__(16) __bf16 As[128 * 32];
  __shared__ __align__(16) __bf16 Bs[128 * 32];
  const int tid = threadIdx.x;
  const int lane = tid & 63, w = tid >> 6;
  const int wr = w >> 1, wc = w & 1;
  const int l4 = lane >> 4, l15 = lane & 15;
  const int m0 = blockIdx.y * 128, n0 = blockIdx.x * 128;

  f32x4 acc[4][4] = {};
  const int srow = lane >> 2;
  const int scol = (lane & 3) * 8;

  for (int k0 = 0; k0 < CDIM; k0 += 32) {
    __syncthreads();
#pragma unroll
    for (int u = 0; u < 2; ++u) {
      const int c = w * 2 + u;
      gload_lds16(A + (size_t)(m0 + c * 16 + srow) * CDIM + k0 + scol,
                  &As[c * 512]);
      gload_lds16(Bw + (size_t)(n0 + c * 16 + srow) * CDIM + k0 + scol,
                  &Bs[c * 512]);
    }
    __syncthreads();
    bf16x8 af[4], bfr[4];
#pragma unroll
    for (int i = 0; i < 4; ++i)
      af[i] = *(const bf16x8*)&As[(wr * 64 + i * 16 + l15) * 32 + l4 * 8];
#pragma unroll
    for (int j = 0; j < 4; ++j)
      bfr[j] = *(const bf16x8*)&Bs[(wc * 64 + j * 16 + l15) * 32 + l4 * 8];
#pragma unroll
    for (int i = 0; i < 4; ++i)
#pragma unroll
      for (int j = 0; j < 4; ++j)
        acc[i][j] = MFMA16(af[i], bfr[j], acc[i][j]);
  }

  const int row0 = m0 + wr * 64;
  if (MODE == 0) {
#pragma unroll
    for (int j = 0; j < 4; ++j) {
      const int n = (n0 + wc * 64 + j * 16) + l15;
      const float bias = b0[n];
#pragma unroll
      for (int i = 0; i < 4; ++i) {
        const int mrow = row0 + i * 16 + l4 * 4;
#pragma unroll
        for (int r = 0; r < 4; ++r)
          Yf[(size_t)(mrow + r) * CDIM + n] = acc[i][j][r] + bias;
      }
    }
  } else {
    const int which = n0 >> 10;  // 0=q 1=k 2=v (block-uniform)
    const float* bias = which == 0 ? b0 : which == 1 ? b1 : b2;
    const int n0c = n0 & 1023;
    if (which == 2) {
      // V^T store: [B][H][Dh][SEQ]
#pragma unroll
      for (int j = 0; j < 4; ++j) {
        const int c = n0c + wc * 64 + j * 16 + l15;
        const int h = c >> 6, dh = c & 63;
        const float bias_v = bias[c];
#pragma unroll
        for (int i = 0; i < 4; ++i) {
          const int mrow = row0 + i * 16 + l4 * 4;
          const int b_ = mrow >> 11, ns = mrow & (SEQ - 1);
          __bf16* p = Vb + ((size_t)(b_ * NH + h) * DH + dh) * SEQ + ns;
          *(unsigned*)p = pk2(acc[i][j][0] + bias_v, acc[i][j][1] + bias_v);
          *(unsigned*)(p + 2) = pk2(acc[i][j][2] + bias_v, acc[i][j][3] + bias_v);
        }
      }
    } else {
      __bf16* Out = which == 0 ? Qb : Kb;
      // Q scale: Dh^-0.5 * log2(e)  (softmax runs in exp2 domain)
      const float scl = which == 0 ? 0.18033688f : 1.0f;
#pragma unroll
      for (int j = 0; j < 4; ++j) {
        const int c = n0c + wc * 64 + j * 16 + l15;
        const int h = c >> 6, dh = c & 63;
        const float bias_v = bias[c];
#pragma unroll
        for (int i = 0; i < 4; ++i) {
          const int mrow = row0 + i * 16 + l4 * 4;
#pragma unroll
          for (int r = 0; r < 4; ++r) {
            const int m = mrow + r;
            const int b_ = m >> 11, ns = m & (SEQ - 1);
            Out[((size_t)(b_ * NH + h) * SEQ + ns) * DH + dh] =
                (__bf16)((acc[i][j][r] + bias_v) * scl);
          }
        }
      }
    }
  }
}

// ---------------------------------------------------------------------------
// Flash attention v6: 4 waves x 32 q-rows, K AND V^T staged in padded LDS
// [64][72] (144B rows: measured 0 bank conflicts in r5), register-staged one
// FULL body ahead, raw s_barrier + lgkmcnt-only (no vmcnt drain -> prefetch
// survives the barrier; the compiler waits on the loads only at the
// consuming ds_write, ~2k cycles after issue).
//
// Race-freedom of the single end-of-body barrier:
//  - body kt reads buf = kt&1; writes kt+1 data into nbuf = buf^1 at the END
//    of body kt (earliest possible position: after barrier(kt-1)).
//  - all waves' reads of nbuf happened in body kt-1, before barrier(kt-1).
//  - a wave reaches body kt only after every wave passed barrier(kt-1)
//    => no wave can still be reading nbuf when it is overwritten.   q.e.d.
// ---------------------------------------------------------------------------
__global__ __launch_bounds__(256) void attn_mfma(
    const __bf16* __restrict__ Qg, const __bf16* __restrict__ Kg,
    const __bf16* __restrict__ VTg, __bf16* __restrict__ AO) {
  __shared__ __align__(16) __bf16 kS[2][64][72];  // [buf][key][d]
  __shared__ __align__(16) __bf16 vS[2][64][72];  // [buf][d][key]
  const int tid = threadIdx.x, lane = tid & 63, w = tid >> 6;
  const int l31 = lane & 31, hi = lane >> 5;
  const int bh = blockIdx.x, qt = blockIdx.y;
  const int b_ = bh >> 4, h_ = bh & 15;

  const __bf16* Qp = Qg + ((size_t)bh * SEQ + qt * 128 + w * 32) * DH;
  const __bf16* Kb = Kg + (size_t)bh * SEQ * DH;
  const __bf16* VT = VTg + (size_t)bh * DH * SEQ;  // [d][seq]

  // Q B-frags: lane holds Q[q=l31][d = t*16 + hi*8 + e]  (pre-scaled)
  bf16x8 q[4];
#pragma unroll
  for (int t = 0; t < 4; ++t)
    q[t] = *(const bf16x8*)(Qp + (size_t)l31 * DH + t * 16 + hi * 8);

  f32x16 o0 = {}, o1 = {};  // O^T: lane q=l31, d = X*32 + (j&3)+8*(j>>2)+4*hi
  float m_i = -1e30f, l_i = 0.f;

  // Staging map: thread -> (row srow = tid>>2, 16-elem chunk sc = (tid&3)*16).
  // K tile kt: rows are keys, source K + (kt*64+srow)*DH + sc   (contiguous)
  // V tile kt: rows are d,    source VT + srow*SEQ + kt*64 + sc
  const int srow = tid >> 2, sc = (tid & 3) * 16;
  const __bf16* Ksrc = Kb + (size_t)srow * DH + sc;
  const __bf16* Vsrc = VT + (size_t)srow * SEQ + sc;

  // ---- prologue: stage tile 0 into buf 0 ----
  {
    bf16x8 a0 = *(const bf16x8*)(Ksrc);
    bf16x8 a1 = *(const bf16x8*)(Ksrc + 8);
    bf16x8 b0 = *(const bf16x8*)(Vsrc);
    bf16x8 b1 = *(const bf16x8*)(Vsrc + 8);
    *(bf16x8*)&kS[0][srow][sc] = a0;
    *(bf16x8*)&kS[0][srow][sc + 8] = a1;
    *(bf16x8*)&vS[0][srow][sc] = b0;
    *(bf16x8*)&vS[0][srow][sc + 8] = b1;
  }
  block_sync_lds();

  auto body = [&](int kt, int buf) {
    const int nbuf = buf ^ 1;
    const int ktn = (kt + 1) & 31;
    // 1. ISSUE next-tile staging loads (consumed at step 5; vmcnt waited
    //    there by the compiler -- ~2k cycles of compute in between)
    bf16x8 ska0 = *(const bf16x8*)(Ksrc + (size_t)ktn * 64 * DH);
    bf16x8 ska1 = *(const bf16x8*)(Ksrc + (size_t)ktn * 64 * DH + 8);
    bf16x8 svb0 = *(const bf16x8*)(Vsrc + ktn * 64);
    bf16x8 svb1 = *(const bf16x8*)(Vsrc + ktn * 64 + 8);
    // 2. QK^T from LDS K: s[X] = S[key = X*32 + (reg&3)+8*(reg>>2)+4*hi][q=l31]
    f32x16 s0 = {}, s1 = {};
    __builtin_amdgcn_s_setprio(1);
#pragma unroll
    for (int t = 0; t < 4; ++t) {
      bf16x8 ka = *(const bf16x8*)&kS[buf][l31][t * 16 + hi * 8];
      s0 = MFMA32(ka, q[t], s0);
    }
#pragma unroll
    for (int t = 0; t < 4; ++t) {
      bf16x8 kc = *(const bf16x8*)&kS[buf][32 + l31][t * 16 + hi * 8];
      s1 = MFMA32(kc, q[t], s1);
    }
    __builtin_amdgcn_s_setprio(0);
    // 3. softmax (exp2 domain; Q pre-scaled by 0.125*log2e)
    float mt[16];
#pragma unroll
    for (int j = 0; j < 16; ++j) mt[j] = fmaxf(s0[j], s1[j]);
#pragma unroll
    for (int st = 8; st > 0; st >>= 1)
#pragma unroll
      for (int j = 0; j < 8; ++j)
        if (j < st) mt[j] = fmaxf(mt[j], mt[j + st]);
    float mx = fmaxf(mt[0], __shfl_xor(mt[0], 32));
    if (!__all(mx <= m_i + 8.0f)) {  // defer-max (P bounded by 2^8)
      const float mnew = fmaxf(m_i, mx);
      const float alpha = __builtin_amdgcn_exp2f(m_i - mnew);
      m_i = mnew;
      l_i *= alpha;
      o0 *= alpha;
      o1 *= alpha;
    }
    unsigned W0[4][2], W1[4][2];
    float psa[4] = {0.f, 0.f, 0.f, 0.f};
#pragma unroll
    for (int m = 0; m < 4; ++m)
#pragma unroll
      for (int j2 = 0; j2 < 2; ++j2) {
        float a0 = __builtin_amdgcn_exp2f(s0[4 * m + 2 * j2] - m_i);
        float a1 = __builtin_amdgcn_exp2f(s0[4 * m + 2 * j2 + 1] - m_i);
        float b0 = __builtin_amdgcn_exp2f(s1[4 * m + 2 * j2] - m_i);
        float b1 = __builtin_amdgcn_exp2f(s1[4 * m + 2 * j2 + 1] - m_i);
        psa[m] += (a0 + a1) + (b0 + b1);
        W0[m][j2] = pk2(a0, a1);
        W1[m][j2] = pk2(b0, b1);
      }
    float ps = (psa[0] + psa[1]) + (psa[2] + psa[3]);
    ps += __shfl_xor(ps, 32);
    l_i += ps;
    // 4a. exchange -> P^T B-frags Bp[ks]: key=ks*16+hi*8+e, col q=l31
    bf16x8 Bp[4];
#pragma unroll
    for (int X = 0; X < 2; ++X)
#pragma unroll
      for (int k2 = 0; k2 < 2; ++k2) {
        union { unsigned u[4]; bf16x8 v; } bb;
#pragma unroll
        for (int j2 = 0; j2 < 2; ++j2) {
          const unsigned a = X ? W1[2 * k2][j2] : W0[2 * k2][j2];
          const unsigned b = X ? W1[2 * k2 + 1][j2] : W0[2 * k2 + 1][j2];
          const unsigned snd = hi ? a : b;
          const unsigned rcv = __shfl_xor(snd, 32);
          bb.u[j2] = hi ? rcv : a;
          bb.u[2 + j2] = hi ? b : rcv;
        }
        Bp[X * 2 + k2] = bb.v;
      }
    // 4b. PV from LDS V^T
    __builtin_amdgcn_s_setprio(1);
#pragma unroll
    for (int ks = 0; ks < 4; ++ks) {
      bf16x8 va0 = *(const bf16x8*)&vS[buf][l31][ks * 16 + hi * 8];
      bf16x8 va1 = *(const bf16x8*)&vS[buf][32 + l31][ks * 16 + hi * 8];
      o0 = MFMA32(va0, Bp[ks], o0);
      o1 = MFMA32(va1, Bp[ks], o1);
    }
    __builtin_amdgcn_s_setprio(0);
    // 5. write next tile into nbuf (earliest legal position is after
    //    barrier(kt-1) -- see header proof; compiler waits vmcnt here)
    *(bf16x8*)&kS[nbuf][srow][sc] = ska0;
    *(bf16x8*)&kS[nbuf][srow][sc + 8] = ska1;
    *(bf16x8*)&vS[nbuf][srow][sc] = svb0;
    *(bf16x8*)&vS[nbuf][srow][sc + 8] = svb1;
    // 6. raw barrier (lgkm only -- next body's staging loads stay in flight)
    block_sync_lds();
  };

#pragma unroll 1
  for (int kt2 = 0; kt2 < 16; ++kt2) {
    body(2 * kt2, 0);
    body(2 * kt2 + 1, 1);
  }

  // epilogue: lane q=l31; d = X*32 + 8*(u>>1) + 4*hi + 2*(u&1) for reg pair
  // (2u, 2u+1); pack pairs, u32 stores to AO[b, q, h*64 + d].
  const float inv = 1.f / l_i;
  const int qglob = qt * 128 + w * 32 + l31;
  __bf16* aorow = AO + ((size_t)(b_ * SEQ) + qglob) * CDIM + h_ * DH;
#pragma unroll
  for (int u = 0; u < 8; ++u) {
    const int dbase = 8 * (u >> 1) + 4 * hi + 2 * (u & 1);
    *(unsigned*)(aorow + dbase) = pk2(o0[2 * u] * inv, o0[2 * u + 1] * inv);
    *(unsigned*)(aorow + 32 + dbase) = pk2(o1[2 * u] * inv, o1[2 * u + 1] * inv);
  }
}

// ---------------------------------------------------------------------------
extern "C" void kernel_launch(void* const* d_in, const int* in_sizes, int n_in,
                              void* d_out, int out_size, void* d_ws,
                              size_t ws_size, hipStream_t stream) {
  const float* x  = (const float*)d_in[0];
  const float* Wq = (const float*)d_in[1];
  const float* bq = (const float*)d_in[2];
  const float* Wk = (const float*)d_in[3];
  const float* bk = (const float*)d_in[4];
  const float* Wv = (const float*)d_in[5];
  const float* bv = (const float*)d_in[6];
  const float* Wo = (const float*)d_in[7];
  const float* bo = (const float*)d_in[8];
  float* out = (float*)d_out;

  __bf16* xb   = (__bf16*)d_ws;
  __bf16* wall = xb + (size_t)Mrows * CDIM;
  __bf16* Qb   = wall + (size_t)4 * CDIM * CDIM;
  __bf16* Kb   = Qb + (size_t)Mrows * CDIM;
  __bf16* Vt   = Kb + (size_t)Mrows * CDIM;   // V^T [B][H][Dh][SEQ]
  __bf16* AO   = Vt + (size_t)Mrows * CDIM;

  cast_inputs<<<2048, 256, 0, stream>>>(x, Wq, Wk, Wv, Wo, xb, wall);
  gemm_mfma<1><<<dim3(24, 64), 256, 0, stream>>>(xb, wall, bq, bk, bv, Qb, Kb,
                                                 Vt, nullptr);
  attn_mfma<<<dim3(Bn * NH, SEQ / 128), 256, 0, stream>>>(Qb, Kb, Vt, AO);
  gemm_mfma<0><<<dim3(8, 64), 256, 0, stream>>>(
      AO, wall + (size_t)3 * CDIM * CDIM, bo, nullptr, nullptr, nullptr,
      nullptr, nullptr, out);
}

// Round 10
// 307.851 us; speedup vs baseline: 1.4323x; 1.0483x over previous
//
#include <hip/hip_runtime.h>
#include <hip/hip_bf16.h>
#include <cstddef>
#include <cstdint>

namespace {
constexpr int Bn = 4, SEQ = 2048, CDIM = 1024, NH = 16, DH = 64;
constexpr int Mrows = Bn * CDIM * 2 / 1;  // placeholder avoided; real below
}
// (real constant)
static constexpr int MrowsC = 4 * 2048;  // B*N = 8192

using bf16x8 = __attribute__((ext_vector_type(8))) __bf16;
using f32x4  = __attribute__((ext_vector_type(4))) float;
using f32x16 = __attribute__((ext_vector_type(16))) float;

#define MFMA16(a, b, c) __builtin_amdgcn_mfma_f32_16x16x32_bf16(a, b, c, 0, 0, 0)
#define MFMA32(a, b, c) __builtin_amdgcn_mfma_f32_32x32x16_bf16(a, b, c, 0, 0, 0)

__device__ __forceinline__ void gload_lds16(const __bf16* g, __bf16* l) {
  __builtin_amdgcn_global_load_lds(
      (const __attribute__((address_space(1))) void*)g,
      (__attribute__((address_space(3))) void*)l, 16, 0, 0);
}

__device__ __forceinline__ unsigned pk2(float a, float b) {
  union { __bf16 h[2]; unsigned u; } x;
  x.h[0] = (__bf16)a; x.h[1] = (__bf16)b;
  return x.u;
}

// Raw barrier: waits own DS ops but does NOT drain vmcnt (T4).
__device__ __forceinline__ void block_sync_lds() {
  asm volatile("s_waitcnt lgkmcnt(0)" ::: "memory");
  __builtin_amdgcn_s_barrier();
}

// ---------------------------------------------------------------------------
// Cast x and the 4 weight matrices to bf16.  wall rows: [Wq;Wk;Wv;Wo].
// ---------------------------------------------------------------------------
__global__ __launch_bounds__(256) void cast_inputs(
    const float* __restrict__ x, const float* __restrict__ wq,
    const float* __restrict__ wk, const float* __restrict__ wv,
    const float* __restrict__ wo, __bf16* __restrict__ xb,
    __bf16* __restrict__ wall) {
  constexpr int X4 = MrowsC * CDIM / 4;  // 2M float4
  constexpr int W4 = CDIM * CDIM / 4;    // 256K float4 (== 1<<18)
  constexpr int total = X4 + 4 * W4;
  for (int i = blockIdx.x * 256 + threadIdx.x; i < total; i += gridDim.x * 256) {
    const float4* src;
    __bf16* dst;
    int o;
    if (i < X4) {
      src = (const float4*)x; dst = xb; o = i;
    } else {
      int j = i - X4;
      int w = j >> 18;
      o = j & (W4 - 1);
      src = (const float4*)(w == 0 ? wq : w == 1 ? wk : w == 2 ? wv : wo);
      dst = wall + (size_t)w * (CDIM * CDIM);
    }
    float4 v = src[o];
    union { __bf16 h[4]; ushort4 u4; } pk;
    pk.h[0] = (__bf16)v.x; pk.h[1] = (__bf16)v.y;
    pk.h[2] = (__bf16)v.z; pk.h[3] = (__bf16)v.w;
    *(ushort4*)(dst + (size_t)o * 4) = pk.u4;
  }
}

// ---------------------------------------------------------------------------
// bf16 MFMA GEMM (m97 structure, verified rounds 3-9) + XCD-chunked swizzle
// + LDS-transposed coalesced V^T epilogue.
// MODE 1: N=3072 fused QKV.  Q scaled by 0.125*log2e (exp2-domain softmax)
//   and K -> [B,H,N,Dh];  V -> TRANSPOSED [B,H,Dh,SEQ] via LDS transpose.
// MODE 0: N=1024 -> fp32 out + bias, row-major [M,1024]
// ---------------------------------------------------------------------------
template <int MODE>
__global__ __launch_bounds__(256) void gemm_mfma(
    const __bf16* __restrict__ A, const __bf16* __restrict__ Bw,
    const float* __restrict__ b0, const float* __restrict__ b1,
    const float* __restrict__ b2, __bf16* __restrict__ Qb,
    __bf16* __restrict__ Kb, __bf16* __restrict__ Vb,
    float* __restrict__ Yf) {
  __shared__ __align__(16) __bf16 smem[2 * 128 * 32];  // As | Bs; reused by epi
  __bf16* As = smem;
  __bf16* Bs = smem + 128 * 32;
  const int tid = threadIdx.x;
  const int lane = tid & 63, w = tid >> 6;
  const int wr = w >> 1, wc = w & 1;
  const int l4 = lane >> 4, l15 = lane & 15;

  // XCD-chunked swizzle: XCD k (hw bids == k mod 8) executes a contiguous
  // chunk of the work space -> neighbor blocks (sharing A panel) share L2.
  const int nwg = gridDim.x * gridDim.y;          // 1536 or 512; % 8 == 0
  int bid = blockIdx.x + gridDim.x * blockIdx.y;
  bid = (bid & 7) * (nwg >> 3) + (bid >> 3);
  const int m0 = (bid / gridDim.x) * 128, n0 = (bid % gridDim.x) * 128;

  f32x4 acc[4][4] = {};
  const int srow = lane >> 2;
  const int scol = (lane & 3) * 8;

  for (int k0 = 0; k0 < CDIM; k0 += 32) {
    __syncthreads();
#pragma unroll
    for (int u = 0; u < 2; ++u) {
      const int c = w * 2 + u;
      gload_lds16(A + (size_t)(m0 + c * 16 + srow) * CDIM + k0 + scol,
                  &As[c * 512]);
      gload_lds16(Bw + (size_t)(n0 + c * 16 + srow) * CDIM + k0 + scol,
                  &Bs[c * 512]);
    }
    __syncthreads();
    bf16x8 af[4], bfr[4];
#pragma unroll
    for (int i = 0; i < 4; ++i)
      af[i] = *(const bf16x8*)&As[(wr * 64 + i * 16 + l15) * 32 + l4 * 8];
#pragma unroll
    for (int j = 0; j < 4; ++j)
      bfr[j] = *(const bf16x8*)&Bs[(wc * 64 + j * 16 + l15) * 32 + l4 * 8];
#pragma unroll
    for (int i = 0; i < 4; ++i)
#pragma unroll
      for (int j = 0; j < 4; ++j)
        acc[i][j] = MFMA16(af[i], bfr[j], acc[i][j]);
  }

  const int row0 = m0 + wr * 64;
  if (MODE == 0) {
#pragma unroll
    for (int j = 0; j < 4; ++j) {
      const int n = (n0 + wc * 64 + j * 16) + l15;
      const float bias = b0[n];
#pragma unroll
      for (int i = 0; i < 4; ++i) {
        const int mrow = row0 + i * 16 + l4 * 4;
#pragma unroll
        for (int r = 0; r < 4; ++r)
          Yf[(size_t)(mrow + r) * CDIM + n] = acc[i][j][r] + bias;
      }
    }
  } else {
    const int which = n0 >> 10;  // 0=q 1=k 2=v (block-uniform)
    const float* bias = which == 0 ? b0 : which == 1 ? b1 : b2;
    const int n0c = n0 & 1023;
    if (which == 2) {
      // ---- V^T epilogue: LDS transpose -> coalesced 16B stores ----
      // scratch[32][136] bf16 (8.7 KB, aliases staging LDS, 272B row stride:
      // 16B-aligned, read conflicts 2-way (free), write b64 <=4-way).
      __bf16 (*scr)[136] = reinterpret_cast<__bf16(*)[136]>(smem);
      const int wcol = wc * 16 + l15;                // write col
      const int g = tid >> 4, r8 = (tid & 15) * 8;   // read/store map
      const int b_ = m0 >> 11, ns0 = m0 & (SEQ - 1);
#pragma unroll
      for (int j = 0; j < 4; ++j) {
        const float bias_v = bias[n0c + wc * 64 + j * 16 + l15];
        __syncthreads();  // previous slice's readers (or MFMA LDS reads) done
#pragma unroll
        for (int i = 0; i < 4; ++i) {
          const int rw = wr * 64 + i * 16 + l4 * 4;  // 4 consecutive rows
          union { __bf16 h[4]; ushort4 u4; } pv;
#pragma unroll
          for (int r = 0; r < 4; ++r) pv.h[r] = (__bf16)(acc[i][j][r] + bias_v);
          *(ushort4*)&scr[wcol][rw] = pv.u4;  // 8B store, aligned (272%8==0)
        }
        __syncthreads();
#pragma unroll
        for (int p = 0; p < 2; ++p) {
          const int cl2 = p * 16 + g;
          const int cv = n0c + p * 64 + j * 16 + (cl2 & 15);
          const int h = cv >> 6, dh = cv & 63;
          bf16x8 vv = *(const bf16x8*)&scr[cl2][r8];
          *(bf16x8*)(Vb + ((size_t)(b_ * NH + h) * DH + dh) * SEQ + ns0 + r8) =
              vv;
        }
      }
    } else {
      __bf16* Out = which == 0 ? Qb : Kb;
      // Q scale: Dh^-0.5 * log2(e)  (softmax runs in exp2 domain)
      const float scl = which == 0 ? 0.18033688f : 1.0f;
#pragma unroll
      for (int j = 0; j < 4; ++j) {
        const int c = n0c + wc * 64 + j * 16 + l15;
        const int h = c >> 6, dh = c & 63;
        const float bias_v = bias[c];
#pragma unroll
        for (int i = 0; i < 4; ++i) {
          const int mrow = row0 + i * 16 + l4 * 4;
#pragma unroll
          for (int r = 0; r < 4; ++r) {
            const int m = mrow + r;
            const int b_ = m >> 11, ns = m & (SEQ - 1);
            Out[((size_t)(b_ * NH + h) * SEQ + ns) * DH + dh] =
                (__bf16)((acc[i][j][r] + bias_v) * scl);
          }
        }
      }
    }
  }
}

// ---------------------------------------------------------------------------
// Flash attention v6 (verified round 9) + XCD swizzle so the 16 blocks
// sharing one (b,h)'s K/V land on one XCD (KV footprint 8*512KB = 4MB = L2).
// ---------------------------------------------------------------------------
__global__ __launch_bounds__(256) void attn_mfma(
    const __bf16* __restrict__ Qg, const __bf16* __restrict__ Kg,
    const __bf16* __restrict__ VTg, __bf16* __restrict__ AO) {
  __shared__ __align__(16) __bf16 kS[2][64][72];  // [buf][key][d]
  __shared__ __align__(16) __bf16 vS[2][64][72];  // [buf][d][key]
  const int tid = threadIdx.x, lane = tid & 63, w = tid >> 6;
  const int l31 = lane & 31, hi = lane >> 5;
  // swizzle: 1024 blocks; XCD k gets wk in [k*128,(k+1)*128) = bh in
  // [k*8,k*8+8) x all 16 qt  (bh = wk>>4, qt = wk&15)
  int bidl = blockIdx.x + 64 * blockIdx.y;
  const int wk = (bidl & 7) * 128 + (bidl >> 3);
  const int bh = wk >> 4, qt = wk & 15;
  const int b_ = bh >> 4, h_ = bh & 15;

  const __bf16* Qp = Qg + ((size_t)bh * SEQ + qt * 128 + w * 32) * DH;
  const __bf16* Kb = Kg + (size_t)bh * SEQ * DH;
  const __bf16* VT = VTg + (size_t)bh * DH * SEQ;  // [d][seq]

  bf16x8 q[4];
#pragma unroll
  for (int t = 0; t < 4; ++t)
    q[t] = *(const bf16x8*)(Qp + (size_t)l31 * DH + t * 16 + hi * 8);

  f32x16 o0 = {}, o1 = {};  // O^T: lane q=l31, d = X*32 + (j&3)+8*(j>>2)+4*hi
  float m_i = -1e30f, l_i = 0.f;

  const int srow = tid >> 2, sc = (tid & 3) * 16;
  const __bf16* Ksrc = Kb + (size_t)srow * DH + sc;
  const __bf16* Vsrc = VT + (size_t)srow * SEQ + sc;

  {  // prologue: stage tile 0 into buf 0
    bf16x8 a0 = *(const bf16x8*)(Ksrc);
    bf16x8 a1 = *(const bf16x8*)(Ksrc + 8);
    bf16x8 b0 = *(const bf16x8*)(Vsrc);
    bf16x8 b1 = *(const bf16x8*)(Vsrc + 8);
    *(bf16x8*)&kS[0][srow][sc] = a0;
    *(bf16x8*)&kS[0][srow][sc + 8] = a1;
    *(bf16x8*)&vS[0][srow][sc] = b0;
    *(bf16x8*)&vS[0][srow][sc + 8] = b1;
  }
  block_sync_lds();

  auto body = [&](int kt, int buf) {
    const int nbuf = buf ^ 1;
    const int ktn = (kt + 1) & 31;
    // 1. issue next-tile staging loads (vmcnt waited only at step 5)
    bf16x8 ska0 = *(const bf16x8*)(Ksrc + (size_t)ktn * 64 * DH);
    bf16x8 ska1 = *(const bf16x8*)(Ksrc + (size_t)ktn * 64 * DH + 8);
    bf16x8 svb0 = *(const bf16x8*)(Vsrc + ktn * 64);
    bf16x8 svb1 = *(const bf16x8*)(Vsrc + ktn * 64 + 8);
    // 2. QK^T from LDS K
    f32x16 s0 = {}, s1 = {};
    __builtin_amdgcn_s_setprio(1);
#pragma unroll
    for (int t = 0; t < 4; ++t) {
      bf16x8 ka = *(const bf16x8*)&kS[buf][l31][t * 16 + hi * 8];
      s0 = MFMA32(ka, q[t], s0);
    }
#pragma unroll
    for (int t = 0; t < 4; ++t) {
      bf16x8 kc = *(const bf16x8*)&kS[buf][32 + l31][t * 16 + hi * 8];
      s1 = MFMA32(kc, q[t], s1);
    }
    __builtin_amdgcn_s_setprio(0);
    // 3. softmax (exp2 domain; Q pre-scaled by 0.125*log2e)
    float mt[16];
#pragma unroll
    for (int j = 0; j < 16; ++j) mt[j] = fmaxf(s0[j], s1[j]);
#pragma unroll
    for (int st = 8; st > 0; st >>= 1)
#pragma unroll
      for (int j = 0; j < 8; ++j)
        if (j < st) mt[j] = fmaxf(mt[j], mt[j + st]);
    float mx = fmaxf(mt[0], __shfl_xor(mt[0], 32));
    if (!__all(mx <= m_i + 8.0f)) {  // defer-max
      const float mnew = fmaxf(m_i, mx);
      const float alpha = __builtin_amdgcn_exp2f(m_i - mnew);
      m_i = mnew;
      l_i *= alpha;
      o0 *= alpha;
      o1 *= alpha;
    }
    unsigned W0[4][2], W1[4][2];
    float psa[4] = {0.f, 0.f, 0.f, 0.f};
#pragma unroll
    for (int m = 0; m < 4; ++m)
#pragma unroll
      for (int j2 = 0; j2 < 2; ++j2) {
        float a0 = __builtin_amdgcn_exp2f(s0[4 * m + 2 * j2] - m_i);
        float a1 = __builtin_amdgcn_exp2f(s0[4 * m + 2 * j2 + 1] - m_i);
        float b0 = __builtin_amdgcn_exp2f(s1[4 * m + 2 * j2] - m_i);
        float b1 = __builtin_amdgcn_exp2f(s1[4 * m + 2 * j2 + 1] - m_i);
        psa[m] += (a0 + a1) + (b0 + b1);
        W0[m][j2] = pk2(a0, a1);
        W1[m][j2] = pk2(b0, b1);
      }
    float ps = (psa[0] + psa[1]) + (psa[2] + psa[3]);
    ps += __shfl_xor(ps, 32);
    l_i += ps;
    // 4a. exchange -> P^T B-frags
    bf16x8 Bp[4];
#pragma unroll
    for (int X = 0; X < 2; ++X)
#pragma unroll
      for (int k2 = 0; k2 < 2; ++k2) {
        union { unsigned u[4]; bf16x8 v; } bb;
#pragma unroll
        for (int j2 = 0; j2 < 2; ++j2) {
          const unsigned a = X ? W1[2 * k2][j2] : W0[2 * k2][j2];
          const unsigned b = X ? W1[2 * k2 + 1][j2] : W0[2 * k2 + 1][j2];
          const unsigned snd = hi ? a : b;
          const unsigned rcv = __shfl_xor(snd, 32);
          bb.u[j2] = hi ? rcv : a;
          bb.u[2 + j2] = hi ? b : rcv;
        }
        Bp[X * 2 + k2] = bb.v;
      }
    // 4b. PV from LDS V^T
    __builtin_amdgcn_s_setprio(1);
#pragma unroll
    for (int ks = 0; ks < 4; ++ks) {
      bf16x8 va0 = *(const bf16x8*)&vS[buf][l31][ks * 16 + hi * 8];
      bf16x8 va1 = *(const bf16x8*)&vS[buf][32 + l31][ks * 16 + hi * 8];
      o0 = MFMA32(va0, Bp[ks], o0);
      o1 = MFMA32(va1, Bp[ks], o1);
    }
    __builtin_amdgcn_s_setprio(0);
    // 5. write next tile into nbuf (compiler waits vmcnt here)
    *(bf16x8*)&kS[nbuf][srow][sc] = ska0;
    *(bf16x8*)&kS[nbuf][srow][sc + 8] = ska1;
    *(bf16x8*)&vS[nbuf][srow][sc] = svb0;
    *(bf16x8*)&vS[nbuf][srow][sc + 8] = svb1;
    // 6. raw barrier (lgkm only)
    block_sync_lds();
  };

#pragma unroll 1
  for (int kt2 = 0; kt2 < 16; ++kt2) {
    body(2 * kt2, 0);
    body(2 * kt2 + 1, 1);
  }

  const float inv = 1.f / l_i;
  const int qglob = qt * 128 + w * 32 + l31;
  __bf16* aorow = AO + ((size_t)(b_ * SEQ) + qglob) * CDIM + h_ * DH;
#pragma unroll
  for (int u = 0; u < 8; ++u) {
    const int dbase = 8 * (u >> 1) + 4 * hi + 2 * (u & 1);
    *(unsigned*)(aorow + dbase) = pk2(o0[2 * u] * inv, o0[2 * u + 1] * inv);
    *(unsigned*)(aorow + 32 + dbase) = pk2(o1[2 * u] * inv, o1[2 * u + 1] * inv);
  }
}

// ---------------------------------------------------------------------------
extern "C" void kernel_launch(void* const* d_in, const int* in_sizes, int n_in,
                              void* d_out, int out_size, void* d_ws,
                              size_t ws_size, hipStream_t stream) {
  const float* x  = (const float*)d_in[0];
  const float* Wq = (const float*)d_in[1];
  const float* bq = (const float*)d_in[2];
  const float* Wk = (const float*)d_in[3];
  const float* bk = (const float*)d_in[4];
  const float* Wv = (const float*)d_in[5];
  const float* bv = (const float*)d_in[6];
  const float* Wo = (const float*)d_in[7];
  const float* bo = (const float*)d_in[8];
  float* out = (float*)d_out;

  __bf16* xb   = (__bf16*)d_ws;
  __bf16* wall = xb + (size_t)MrowsC * CDIM;
  __bf16* Qb   = wall + (size_t)4 * CDIM * CDIM;
  __bf16* Kb   = Qb + (size_t)MrowsC * CDIM;
  __bf16* Vt   = Kb + (size_t)MrowsC * CDIM;   // V^T [B][H][Dh][SEQ]
  __bf16* AO   = Vt + (size_t)MrowsC * CDIM;

  cast_inputs<<<2048, 256, 0, stream>>>(x, Wq, Wk, Wv, Wo, xb, wall);
  gemm_mfma<1><<<dim3(24, 64), 256, 0, stream>>>(xb, wall, bq, bk, bv, Qb, Kb,
                                                 Vt, nullptr);
  attn_mfma<<<dim3(64, 16), 256, 0, stream>>>(Qb, Kb, Vt, AO);
  gemm_mfma<0><<<dim3(8, 64), 256, 0, stream>>>(
      AO, wall + (size_t)3 * CDIM * CDIM, bo, nullptr, nullptr, nullptr,
      nullptr, nullptr, out);
}